// Round 7
// baseline (317.297 us; speedup 1.0000x reference)
//
#include <hip/hip_runtime.h>

// CTC greedy decoder: argmax over V, then per-row unique_consecutive + blank-drop + compact.
// B=64, T=2048, V=512 (fp32 probs, int32 lengths, int32 outputs).
//
// R7 = R6 (best known, 311.6 us) with argmax re-launched for CONCURRENCY:
//  - __launch_bounds__(256, 8): 8 waves/SIMD = 32 waves/CU (2x R4's measured 45%
//    occupancy), VGPR cap 64 so all 8 float4 load destinations can be live at
//    once (R4 showed VGPR_Count=32 -- the compiler had serialized the load chain
//    into small batches; per-wave MLP was a fraction of the intended 8 KB).
//  - Grid = 2048 blocks (exactly 8 blocks/CU), grid-stride over the 8192
//    16-row groups (4 iters/block). Length-skip retained per-iteration
//    (uniform branch; skipped groups issue no loads but the block stays
//    resident for its next group).
// Theory: the ~1.4 TB/s effective read wall seen in R0/R3/R4/R5/R6 is a
// concurrency (Little's law) limit, not a bandwidth or VALU limit -- R4's
// counters showed HBM 690 GB/s, VALU 3.5%, 0 conflicts, occupancy 45%.

#define VDIM 512
#define TDIM 2048

typedef float vfloat4 __attribute__((ext_vector_type(4)));

// Block = 256 threads = 4 waves; each block-iteration handles 16 consecutive
// rows (one group; groups never straddle batches since 16 | 2048).
// Lane (g,s): g = row-within-wave (0..3), s = 16-lane sublane (0..15).
// Lane s of a row reads float4s j*16+s in ascending index order -> strict >
// comparisons keep the first occurrence, matching jnp.argmax.
__global__ __launch_bounds__(256, 8) void argmax_rows(const float* __restrict__ probs,
                                                      const int* __restrict__ lengths,
                                                      int* __restrict__ tokens,
                                                      int nrows) {
    const int tid = threadIdx.x;
    const int w = tid >> 6;              // wave id within block
    const int l = tid & 63;
    const int g = l >> 4;                // row group within wave (0..3)
    const int s = l & 15;                // sublane within row (0..15)

    const int ngroups = nrows >> 4;      // 8192
    for (int grp = blockIdx.x; grp < ngroups; grp += gridDim.x) {
        // length-skip: all 16 rows of this group share batch b
        const int b = grp >> 7;                  // (grp*16) / TDIM
        const int t0 = (grp & 127) << 4;         // (grp*16) % TDIM
        if (t0 >= lengths[b]) continue;          // uniform; dead rows

        const int row = grp * 16 + w * 4 + g;
        const vfloat4* p = (const vfloat4*)(probs + (size_t)row * VDIM);

        // 8 independent nontemporal 16B loads; with the 64-VGPR budget all 8
        // destinations are live -> 8 KB in flight per wave.
        vfloat4 v[8];
        #pragma unroll
        for (int j = 0; j < 8; j++) {
            v[j] = __builtin_nontemporal_load(&p[j * 16 + s]);
        }

        // Local argmax over 32 elements in ascending-index order.
        float bv = v[0].x;
        int bi = s * 4;
        #pragma unroll
        for (int j = 0; j < 8; j++) {
            const int base = j * 64 + s * 4;
            const vfloat4 a = v[j];
            if (j > 0) { if (a.x > bv) { bv = a.x; bi = base; } }
            if (a.y > bv) { bv = a.y; bi = base + 1; }
            if (a.z > bv) { bv = a.z; bi = base + 2; }
            if (a.w > bv) { bv = a.w; bi = base + 3; }
        }

        // Butterfly across the 16-lane group; ties -> lower index.
        #pragma unroll
        for (int off = 8; off > 0; off >>= 1) {
            float ov = __shfl_xor(bv, off, 16);
            int   oi = __shfl_xor(bi, off, 16);
            if (ov > bv || (ov == bv && oi < bi)) { bv = ov; bi = oi; }
        }

        // 16 consecutive dwords per group (coalesced).
        if (s == 0) tokens[row] = bi;
    }
}

// One block (256 threads) per batch row; 8 tokens/thread over T=2048.
// keep = (t < len) && (tok != 0) && (tok != prev); prefix-scan; compact left; zero tail.
// All global READS happen before the first __syncthreads (which drains vmcnt on
// gfx950), so the kernel is safe when `tokens` aliases `out` (in-place compact).
// Token slots at t >= len may hold stale poison (length-skip); keep masks them.
__global__ __launch_bounds__(256) void ctc_compact(const int* __restrict__ tokens,
                                                   const int* __restrict__ lengths,
                                                   int* __restrict__ out,
                                                   int* __restrict__ out_lengths) {
    const int b = blockIdx.x;
    const int tid = threadIdx.x;
    const int t0 = tid * 8;

    const int* row = tokens + (size_t)b * TDIM;

    // load 8 tokens (2x int4) + predecessor
    int4 lo = ((const int4*)(row + t0))[0];
    int4 hi = ((const int4*)(row + t0))[1];
    int tok[8] = { lo.x, lo.y, lo.z, lo.w, hi.x, hi.y, hi.z, hi.w };
    int prev = (t0 == 0) ? -1 : row[t0 - 1];

    int len = lengths[b];
    if (len < 0) len = 0;
    if (len > TDIM) len = TDIM;

    // thread-local keep flags + exclusive positions
    int pos[8];
    unsigned kb = 0;
    int c = 0;
    #pragma unroll
    for (int j = 0; j < 8; j++) {
        int t = t0 + j;
        int tk = tok[j];
        bool keep = (t < len) & (tk != 0) & (tk != prev);
        pos[j] = c;
        if (keep) { kb |= (1u << j); c++; }
        prev = tk;
    }

    // block exclusive scan: wave shuffle scan + 4-wave LDS combine
    int lane = tid & 63;
    int wid = tid >> 6;
    int incl = c;
    #pragma unroll
    for (int off = 1; off < 64; off <<= 1) {
        int n = __shfl_up(incl, off, 64);
        if (lane >= off) incl += n;
    }
    __shared__ int wsum[4];
    if (lane == 63) wsum[wid] = incl;
    __syncthreads();
    int wbase = 0;
    #pragma unroll
    for (int ww = 0; ww < 4; ww++) {
        int ssum = wsum[ww];
        if (ww < wid) wbase += ssum;
    }
    int excl = wbase + incl - c;
    int total = wsum[0] + wsum[1] + wsum[2] + wsum[3];

    // scatter kept tokens to [0, total)
    int* orow = out + (size_t)b * TDIM;
    #pragma unroll
    for (int j = 0; j < 8; j++) {
        if ((kb >> j) & 1u) orow[excl + pos[j]] = tok[j];
    }
    // zero-fill [total, T)
    for (int t = total + tid; t < TDIM; t += 256) orow[t] = 0;

    if (tid == 0) out_lengths[b] = total;
}

extern "C" void kernel_launch(void* const* d_in, const int* in_sizes, int n_in,
                              void* d_out, int out_size, void* d_ws, size_t ws_size,
                              hipStream_t stream) {
    (void)d_ws; (void)ws_size; (void)n_in; (void)out_size;
    const float* probs = (const float*)d_in[0];
    const int* lengths = (const int*)d_in[1];
    int* out = (int*)d_out;

    const int B = in_sizes[1];              // 64
    const int nrows = in_sizes[0] / VDIM;   // B*T = 131072

    // tokens scratch aliases d_out (in-place): argmax fills out[0..B*T) for
    // t < lengths[b]; ctc_compact then compacts each row in place.
    int* tokens = out;

    // 2048 blocks = exactly 8 blocks/CU; grid-stride over 8192 groups.
    argmax_rows<<<2048, 256, 0, stream>>>(probs, lengths, tokens, nrows);
    ctc_compact<<<B, 256, 0, stream>>>(tokens, lengths, out, out + nrows);
}